// Round 8
// baseline (559.016 us; speedup 1.0000x reference)
//
#include <hip/hip_runtime.h>
#include <hip/hip_bf16.h>

#define NROWS 131072
#define DIN   768
#define DD    512
#define KK    256

#define BM    64
#define BK    32
#define NSTEP 24            // DIN/BK
#define MARGIN_TH 1e-3f

typedef __attribute__((ext_vector_type(8))) short  short8;
typedef __attribute__((ext_vector_type(8))) unsigned short ushort8;
typedef __attribute__((ext_vector_type(4))) float  f32x4;

__device__ __forceinline__ unsigned short f2bf_rn(float x) {
    unsigned int u = __float_as_uint(x);
    unsigned int r = (u + 0x7fffu + ((u >> 16) & 1u)) >> 16;   // RNE
    return (unsigned short)r;
}
__device__ __forceinline__ float bf2f(unsigned short h) {
    return __uint_as_float(((unsigned int)h) << 16);
}

// hi = RNE bf16 of x; lo = truncated bf16 of (x - hi). lo-term is O(2^-9) of x, so
// truncation error (2^-9 of lo) lands at 2^-18 relative -- far below MARGIN_TH.
__device__ __forceinline__ void cvt_store(f32x4 a, f32x4 b,
                                          unsigned short* hd, unsigned short* ldst) {
    ushort8 hv, lv;
#pragma unroll
    for (int j = 0; j < 4; ++j) {
        unsigned short h = f2bf_rn(a[j]);
        hv[j] = h; lv[j] = (unsigned short)(__float_as_uint(a[j] - bf2f(h)) >> 16);
    }
#pragma unroll
    for (int j = 0; j < 4; ++j) {
        unsigned short h = f2bf_rn(b[j]);
        hv[j + 4] = h; lv[j + 4] = (unsigned short)(__float_as_uint(b[j] - bf2f(h)) >> 16);
    }
    *(ushort8*)hd = hv;
    *(ushort8*)ldst = lv;
}

// ---------------- pre: 3 roles in one launch ---------------------------------------------
// blocks 0..47   : w2 GEMM  W2[din][col] = -2*dot(enc_w[din,:], cb0[col,:]) -> bf16 hi/lo Wp
// block 48       : c2[col] = -2*enc_b.cb0[col] + ||cb0[col]||^2 ; counter=0
// blocks 49..304 : chain role -> Tdec[k]
// Wp element layout: Wp[(s*2048 + lg*256 + col)*8 + jj] (hi), +8192 elems (lo);
// din = s*32 + lg*8 + jj.
__global__ __launch_bounds__(256) void pre_kernel(const float* __restrict__ enc_w,
                                                  const float* __restrict__ enc_b,
                                                  const float* __restrict__ cb,
                                                  const float* __restrict__ dec_w,
                                                  const float* __restrict__ dec_b,
                                                  unsigned short* __restrict__ Wp,
                                                  float* __restrict__ c2,
                                                  float* __restrict__ Tdec,
                                                  int* __restrict__ counter) {
    const int t = threadIdx.x;
    const int lane = t & 63, wv = t >> 6;

    if (blockIdx.x < 48) {
        // ================= w2 GEMM role =================
        __shared__ float As[64][21];
        __shared__ float Bs[64][21];
        const int din0 = (blockIdx.x >> 2) * 64;
        const int col0 = (blockIdx.x & 3) * 64;
        const int tr = t >> 4, tc = t & 15;          // 16x16 threads, 4x4 micro-tile
        const int lr_ = t >> 2, k4 = (t & 3) * 4;    // staging map

        float acc[4][4];
#pragma unroll
        for (int i = 0; i < 4; ++i)
#pragma unroll
            for (int j = 0; j < 4; ++j) acc[i][j] = 0.f;

        for (int k0 = 0; k0 < DD; k0 += 16) {
            {
                const float* ap = enc_w + (size_t)(din0 + lr_) * DD + k0 + k4;
                const float* bp = cb + (size_t)(col0 + lr_) * DD + k0 + k4;
                f32x4 av = *(const f32x4*)ap;
                f32x4 bv = *(const f32x4*)bp;
                *(f32x4*)&As[lr_][k4] = av;
                *(f32x4*)&Bs[lr_][k4] = bv;
            }
            __syncthreads();
#pragma unroll
            for (int kk = 0; kk < 16; ++kk) {
                float a[4], b[4];
#pragma unroll
                for (int i = 0; i < 4; ++i) a[i] = As[tr * 4 + i][kk];
#pragma unroll
                for (int j = 0; j < 4; ++j) b[j] = Bs[tc * 4 + j][kk];
#pragma unroll
                for (int i = 0; i < 4; ++i)
#pragma unroll
                    for (int j = 0; j < 4; ++j) acc[i][j] = fmaf(a[i], b[j], acc[i][j]);
            }
            __syncthreads();
        }
#pragma unroll
        for (int i = 0; i < 4; ++i) {
            int din = din0 + tr * 4 + i;
            size_t ub = (size_t)(din >> 5) * 2048 + (size_t)((din >> 3) & 3) * 256;
            int jj = din & 7;
#pragma unroll
            for (int j = 0; j < 4; ++j) {
                int col = col0 + tc * 4 + j;
                float w = -2.0f * acc[i][j];
                unsigned short h = f2bf_rn(w);
                unsigned short l = (unsigned short)(__float_as_uint(w - bf2f(h)) >> 16);
                size_t p = (ub + col) * 8 + jj;
                Wp[p] = h;
                Wp[p + 8192] = l;
            }
        }
    } else if (blockIdx.x == 48) {
        // ================= c2 role =================
        __shared__ float bb[DD];
        for (int d = t; d < DD; d += 256) bb[d] = enc_b[d];
        __syncthreads();
        for (int c4 = 0; c4 < 16; ++c4) {
            int col0 = wv * 64 + c4 * 4;
            const float* C0 = cb + (size_t)col0 * DD;
            const float* C1 = C0 + DD;
            const float* C2 = C0 + 2 * DD;
            const float* C3 = C0 + 3 * DD;
            float b0 = 0, b1 = 0, b2 = 0, b3 = 0, n0 = 0, n1 = 0, n2 = 0, n3 = 0;
#pragma unroll
            for (int i = 0; i < 8; ++i) {
                int d = lane + 64 * i;
                float b = bb[d];
                float c0v = C0[d], c1v = C1[d], c2v = C2[d], c3v = C3[d];
                b0 = fmaf(b, c0v, b0); n0 = fmaf(c0v, c0v, n0);
                b1 = fmaf(b, c1v, b1); n1 = fmaf(c1v, c1v, n1);
                b2 = fmaf(b, c2v, b2); n2 = fmaf(c2v, c2v, n2);
                b3 = fmaf(b, c3v, b3); n3 = fmaf(c3v, c3v, n3);
            }
#pragma unroll
            for (int off = 1; off < 64; off <<= 1) {
                b0 += __shfl_xor(b0, off); n0 += __shfl_xor(n0, off);
                b1 += __shfl_xor(b1, off); n1 += __shfl_xor(n1, off);
                b2 += __shfl_xor(b2, off); n2 += __shfl_xor(n2, off);
                b3 += __shfl_xor(b3, off); n3 += __shfl_xor(n3, off);
            }
            if (lane == 0) {
                c2[col0]     = -2.0f * b0 + n0;
                c2[col0 + 1] = -2.0f * b1 + n1;
                c2[col0 + 2] = -2.0f * b2 + n2;
                c2[col0 + 3] = -2.0f * b3 + n3;
            }
        }
        if (t == 0) *counter = 0;
    } else {
        // ================= chain role =================
        int k = blockIdx.x - 49;
        __shared__ float  q[DD];
        __shared__ float  Tsum[DD];
        __shared__ double wbest[4];
        __shared__ int    wbesti[4];
        __shared__ int    sel;

        for (int d = t; d < DD; d += 256) {
            float v = cb[(size_t)k * DD + d];
            q[d] = v; Tsum[d] = v;
        }

        for (int l = 1; l < 4; ++l) {
            __syncthreads();
            const float* C = cb + (size_t)l * KK * DD;
            double best = 1e300; int bi = 1 << 20;
            for (int c4 = 0; c4 < 16; ++c4) {
                int col0 = wv * 64 + c4 * 4;
                const float* C0 = C + (size_t)col0 * DD;
                const float* C1 = C0 + DD;
                const float* C2 = C0 + 2 * DD;
                const float* C3 = C0 + 3 * DD;
                float p0 = 0, p1 = 0, p2 = 0, p3 = 0, n0 = 0, n1 = 0, n2 = 0, n3 = 0;
#pragma unroll
                for (int i = 0; i < 8; ++i) {
                    int d = lane + 64 * i;
                    float qq = q[d];
                    float c0v = C0[d], c1v = C1[d], c2v = C2[d], c3v = C3[d];
                    p0 = fmaf(qq, c0v, p0); n0 = fmaf(c0v, c0v, n0);
                    p1 = fmaf(qq, c1v, p1); n1 = fmaf(c1v, c1v, n1);
                    p2 = fmaf(qq, c2v, p2); n2 = fmaf(c2v, c2v, n2);
                    p3 = fmaf(qq, c3v, p3); n3 = fmaf(c3v, c3v, n3);
                }
                double s0 = -2.0 * (double)p0 + (double)n0;
                double s1 = -2.0 * (double)p1 + (double)n1;
                double s2 = -2.0 * (double)p2 + (double)n2;
                double s3 = -2.0 * (double)p3 + (double)n3;
#pragma unroll
                for (int off = 1; off < 64; off <<= 1) {
                    s0 += __shfl_xor(s0, off);
                    s1 += __shfl_xor(s1, off);
                    s2 += __shfl_xor(s2, off);
                    s3 += __shfl_xor(s3, off);
                }
                if (s0 < best) { best = s0; bi = col0; }
                if (s1 < best) { best = s1; bi = col0 + 1; }
                if (s2 < best) { best = s2; bi = col0 + 2; }
                if (s3 < best) { best = s3; bi = col0 + 3; }
            }
            if (lane == 0) { wbest[wv] = best; wbesti[wv] = bi; }
            __syncthreads();
            if (t == 0) {
                double bv = wbest[0]; int bidx = wbesti[0];
                for (int g = 1; g < 4; ++g)
                    if (wbest[g] < bv || (wbest[g] == bv && wbesti[g] < bidx)) { bv = wbest[g]; bidx = wbesti[g]; }
                sel = bidx;
            }
            __syncthreads();
            const float* Cs = C + (size_t)sel * DD;
            for (int d = t; d < DD; d += 256) {
                float v = Cs[d];
                q[d] = v; Tsum[d] += v;
            }
        }
        __syncthreads();
        for (int n = t; n < DD; n += 256) {
            double a0 = 0, a1 = 0, a2 = 0, a3 = 0;
            for (int d = 0; d < DD; d += 4) {
                a0 += (double)Tsum[d]     * (double)dec_w[(size_t)(d)     * DD + n];
                a1 += (double)Tsum[d + 1] * (double)dec_w[(size_t)(d + 1) * DD + n];
                a2 += (double)Tsum[d + 2] * (double)dec_w[(size_t)(d + 2) * DD + n];
                a3 += (double)Tsum[d + 3] * (double)dec_w[(size_t)(d + 3) * DD + n];
            }
            Tdec[(size_t)k * DD + n] = (float)((double)dec_b[n] + a0 + a1 + a2 + a3);
        }
    }
}

// ---------------- bulk: reg-pipelined MFMA, 3 waves/SIMD target --------------------------
// grid 2048, block 256 (4 waves). Block tile 64 rows x 256 cols; wave tile 64x64 (cg=wv).
// Step s: read X(s) frags from LDS[s&1] | cvt X(s+1) regs->LDS[(s+1)&1] | reload nx=X(s+2)
// | load W(s+1) regs | MFMA with W(s) regs | barrier. Single nx buffer (cvt-then-reload).
__global__ __launch_bounds__(256, 3) void bulk_kernel(const float* __restrict__ X,
                                                      const unsigned short* __restrict__ Wp,
                                                      const float* __restrict__ c2,
                                                      const float* __restrict__ Tdec,
                                                      float* __restrict__ out,
                                                      int* __restrict__ counter,
                                                      int* __restrict__ list) {
    __shared__ __align__(16) unsigned short Xh[2][2048];   // 2 x 4KB (256 units x 16B)
    __shared__ __align__(16) unsigned short Xl[2][2048];   // 2 x 4KB
    __shared__ float Rv1[BM * 4];
    __shared__ float Rv2[BM * 4];
    __shared__ int   Ri1[BM * 4];
    __shared__ int   rowIdx[BM];

    const int t    = threadIdx.x;
    const int lane = t & 63;
    const int wv   = t >> 6;        // col-group 0..3 (64 cols each)
    const int lr   = lane & 15;
    const int lg   = lane >> 4;
    const int row0 = blockIdx.x * BM;

    f32x4 acc[4][4];
#pragma unroll
    for (int rf = 0; rf < 4; ++rf)
#pragma unroll
        for (int cf = 0; cf < 4; ++cf) acc[rf][cf] = (f32x4){0.f, 0.f, 0.f, 0.f};

    // X staging: thread t handles row=t>>2, k-subchunk=(t&3)*8
    const int xrow = t >> 2, xsub = t & 3;
    const float* xp_base = X + (size_t)(row0 + xrow) * DIN + xsub * 8;
    const int xu = (xsub * 64 + xrow) ^ (xsub << 1);   // XOR-swizzled unit (write side)

    // W frag lane-base: u = lg*256 + wv*64 + cf*16 + lr; hi at u*8, lo at (u+1024)*8
    const unsigned short* wlane = Wp + (size_t)(lg * 256 + wv * 64 + lr) * 8;

    f32x4 nxa, nxb;
    short8 wh[2][4], wl[2][4];

    // ---- prologue ----
    {
        f32x4 a = __builtin_nontemporal_load((const f32x4*)xp_base);
        f32x4 b = __builtin_nontemporal_load((const f32x4*)(xp_base + 4));
        cvt_store(a, b, &Xh[0][xu * 8], &Xl[0][xu * 8]);
        // issue X(1)
        nxa = __builtin_nontemporal_load((const f32x4*)(xp_base + BK));
        nxb = __builtin_nontemporal_load((const f32x4*)(xp_base + BK + 4));
        // issue W(0)
#pragma unroll
        for (int cf = 0; cf < 4; ++cf) {
            wh[0][cf] = *(const short8*)(wlane + cf * 128);
            wl[0][cf] = *(const short8*)(wlane + cf * 128 + 8192);
        }
    }
    __syncthreads();

#define HALF(P, S)                                                                          \
    {                                                                                       \
        const int s_ = (S);                                                                 \
        /* read X(s) fragments from LDS[P] */                                               \
        short8 ah[4], al[4];                                                                \
        _Pragma("unroll")                                                                   \
        for (int rf = 0; rf < 4; ++rf) {                                                    \
            int u = (lg * 64 + rf * 16 + lr) ^ (lg << 1);                                   \
            ah[rf] = *(const short8*)&Xh[P][u * 8];                                         \
            al[rf] = *(const short8*)&Xl[P][u * 8];                                         \
        }                                                                                   \
        /* cvt X(s+1) regs -> LDS[P^1], then reload nx = X(s+2) into the same regs */       \
        if (s_ + 1 < NSTEP)                                                                 \
            cvt_store(nxa, nxb, &Xh[(P) ^ 1][xu * 8], &Xl[(P) ^ 1][xu * 8]);                \
        if (s_ + 2 < NSTEP) {                                                               \
            nxa = __builtin_nontemporal_load((const f32x4*)(xp_base + (s_ + 2) * BK));      \
            nxb = __builtin_nontemporal_load((const f32x4*)(xp_base + (s_ + 2) * BK + 4));  \
        }                                                                                   \
        /* issue W(s+1) -> w[P^1] */                                                        \
        if (s_ + 1 < NSTEP) {                                                               \
            const unsigned short* wsrc = wlane + (size_t)(s_ + 1) * 16384;                  \
            _Pragma("unroll")                                                               \
            for (int cf = 0; cf < 4; ++cf) {                                                \
                wh[(P) ^ 1][cf] = *(const short8*)(wsrc + cf * 128);                        \
                wl[(P) ^ 1][cf] = *(const short8*)(wsrc + cf * 128 + 8192);                 \
            }                                                                               \
        }                                                                                   \
        /* MFMA with W(s) regs */                                                           \
        _Pragma("unroll")                                                                   \
        for (int cf = 0; cf < 4; ++cf) {                                                    \
            _Pragma("unroll")                                                               \
            for (int rf = 0; rf < 4; ++rf) {                                                \
                acc[rf][cf] = __builtin_amdgcn_mfma_f32_16x16x32_bf16(al[rf], wh[P][cf], acc[rf][cf], 0, 0, 0); \
                acc[rf][cf] = __builtin_amdgcn_mfma_f32_16x16x32_bf16(ah[rf], wl[P][cf], acc[rf][cf], 0, 0, 0); \
                acc[rf][cf] = __builtin_amdgcn_mfma_f32_16x16x32_bf16(ah[rf], wh[P][cf], acc[rf][cf], 0, 0, 0); \
            }                                                                               \
        }                                                                                   \
        __syncthreads();                                                                    \
    }

#pragma unroll 1
    for (int s2 = 0; s2 < NSTEP / 2; ++s2) {
        HALF(0, 2 * s2);
        HALF(1, 2 * s2 + 1);
    }
#undef HALF

    // --- epilogue: per-row top-2 (C/D layout: col=lane&15, row=(lane>>4)*4+reg) ---
    float c2v[4];
#pragma unroll
    for (int cf = 0; cf < 4; ++cf) c2v[cf] = c2[wv * 64 + cf * 16 + lr];

#pragma unroll
    for (int rf = 0; rf < 4; ++rf) {
#pragma unroll
        for (int reg = 0; reg < 4; ++reg) {
            float v1 = 3.4e38f, v2 = 3.4e38f;
            int   c1 = 1 << 20;
#pragma unroll
            for (int cf = 0; cf < 4; ++cf) {
                float sc = acc[rf][cf][reg] + c2v[cf];
                int col = wv * 64 + cf * 16 + lr;
                if (sc < v1 || (sc == v1 && col < c1)) { v2 = v1; v1 = sc; c1 = col; }
                else if (sc < v2) v2 = sc;
            }
#pragma unroll
            for (int off = 1; off < 16; off <<= 1) {
                float ov1 = __shfl_xor(v1, off);
                float ov2 = __shfl_xor(v2, off);
                int   oc1 = __shfl_xor(c1, off);
                if (ov1 < v1 || (ov1 == v1 && oc1 < c1)) { v2 = fminf(v1, ov2); v1 = ov1; c1 = oc1; }
                else v2 = fminf(v2, ov1);
            }
            if (lr == 0) {
                int r = rf * 16 + lg * 4 + reg;
                Rv1[r * 4 + wv] = v1; Ri1[r * 4 + wv] = c1; Rv2[r * 4 + wv] = v2;
            }
        }
    }
    __syncthreads();

    if (t < BM) {
        float v1 = Rv1[t * 4], v2 = Rv2[t * 4];
        int   c1 = Ri1[t * 4];
#pragma unroll
        for (int g = 1; g < 4; ++g) {
            float bv = Rv1[t * 4 + g], bs = Rv2[t * 4 + g];
            int   bc = Ri1[t * 4 + g];
            if (bv < v1) { v2 = fminf(v1, bs); v1 = bv; c1 = bc; }
            else         { v2 = fminf(v2, bv); }
        }
        rowIdx[t] = c1;
        if (v2 - v1 < MARGIN_TH) {
            int pos = atomicAdd(counter, 1);
            list[pos] = row0 + t;
        }
    }
    __syncthreads();

    // --- gather + write: 64 rows x 512 f32, coalesced f32x4, nontemporal ---
#pragma unroll
    for (int m = 0; m < 32; ++m) {
        int lin = m * 256 + t;            // 0..8191
        int r   = lin >> 7;               // 0..63
        int c4  = (lin & 127) * 4;
        f32x4 v = *(const f32x4*)(Tdec + (size_t)rowIdx[r] * DD + c4);
        __builtin_nontemporal_store(v, (f32x4*)(out + (size_t)(row0 + r) * DD + c4));
    }
}

// ---------------- refine: fp64-exact re-decision for near-tie rows ----------------------
__global__ __launch_bounds__(256) void refine_kernel(const float* __restrict__ X,
                                                     const float* __restrict__ enc_w,
                                                     const float* __restrict__ enc_b,
                                                     const float* __restrict__ cb,
                                                     const float* __restrict__ Tdec,
                                                     float* __restrict__ out,
                                                     const int* __restrict__ counter,
                                                     const int* __restrict__ list) {
    int cnt = *counter;
    __shared__ double r0[DD];
    __shared__ double sv[256];
    __shared__ int    si[256];
    for (int it = blockIdx.x; it < cnt; it += gridDim.x) {
        int n = list[it];
        const float* xr = X + (size_t)n * DIN;
        for (int d = threadIdx.x; d < DD; d += 256) {
            double a0 = 0, a1 = 0, a2 = 0, a3 = 0;
            for (int j = 0; j < DIN; j += 4) {
                a0 += (double)xr[j]     * (double)enc_w[(size_t)(j)     * DD + d];
                a1 += (double)xr[j + 1] * (double)enc_w[(size_t)(j + 1) * DD + d];
                a2 += (double)xr[j + 2] * (double)enc_w[(size_t)(j + 2) * DD + d];
                a3 += (double)xr[j + 3] * (double)enc_w[(size_t)(j + 3) * DD + d];
            }
            r0[d] = (double)enc_b[d] + a0 + a1 + a2 + a3;
        }
        __syncthreads();
        int k = threadIdx.x;
        const float* ck = cb + (size_t)k * DD;
        double d0 = 0, d1 = 0, n0 = 0, n1 = 0;
        for (int d = 0; d < DD; d += 2) {
            double c0 = ck[d], c1 = ck[d + 1];
            d0 += r0[d] * c0;     n0 += c0 * c0;
            d1 += r0[d + 1] * c1; n1 += c1 * c1;
        }
        sv[k] = -2.0 * (d0 + d1) + (n0 + n1); si[k] = k;
        __syncthreads();
        for (int off = 128; off; off >>= 1) {
            if (k < off) {
                double a = sv[k], b = sv[k + off];
                if (b < a || (b == a && si[k + off] < si[k])) { sv[k] = b; si[k] = si[k + off]; }
            }
            __syncthreads();
        }
        int best = si[0];
        for (int c = threadIdx.x; c < DD; c += 256)
            out[(size_t)n * DD + c] = Tdec[(size_t)best * DD + c];
        __syncthreads();
    }
}

extern "C" void kernel_launch(void* const* d_in, const int* in_sizes, int n_in,
                              void* d_out, int out_size, void* d_ws, size_t ws_size,
                              hipStream_t stream) {
    const float* X     = (const float*)d_in[0];
    const float* enc_w = (const float*)d_in[1];
    const float* enc_b = (const float*)d_in[2];
    const float* cb    = (const float*)d_in[3];
    const float* dec_w = (const float*)d_in[4];
    const float* dec_b = (const float*)d_in[5];
    float* out = (float*)d_out;

    char* ws = (char*)d_ws;
    unsigned short* Wp = (unsigned short*)(ws + 0);          // 24*2048*8*2B = 786432
    float* c2      = (float*)(ws + 786432);                  // 1024
    float* Tdec    = (float*)(ws + 787456);                  // 524288
    int*   counter = (int*)  (ws + 1311744);                 // 4 (+pad)
    int*   list    = (int*)  (ws + 1311776);                 // near-tie rows

    hipLaunchKernelGGL(pre_kernel,   dim3(305),        dim3(256), 0, stream,
                       enc_w, enc_b, cb, dec_w, dec_b, Wp, c2, Tdec, counter);
    hipLaunchKernelGGL(bulk_kernel,  dim3(NROWS / BM), dim3(256), 0, stream,
                       X, Wp, c2, Tdec, out, counter, list);
    hipLaunchKernelGGL(refine_kernel, dim3(1024),      dim3(256), 0, stream,
                       X, enc_w, enc_b, cb, Tdec, out, counter, list);
}

// Round 9
// 359.198 us; speedup vs baseline: 1.5563x; 1.5563x over previous
//
#include <hip/hip_runtime.h>
#include <hip/hip_bf16.h>

#define NROWS 131072
#define DIN   768
#define DD    512
#define KK    256

#define BM    64
#define BK    32
#define NSTEP 24            // DIN/BK
#define MARGIN_TH 1e-3f

typedef __attribute__((ext_vector_type(8))) short  short8;
typedef __attribute__((ext_vector_type(8))) unsigned short ushort8;
typedef __attribute__((ext_vector_type(4))) float  f32x4;

__device__ __forceinline__ unsigned short f2bf_rn(float x) {
    unsigned int u = __float_as_uint(x);
    unsigned int r = (u + 0x7fffu + ((u >> 16) & 1u)) >> 16;   // RNE
    return (unsigned short)r;
}
__device__ __forceinline__ float bf2f(unsigned short h) {
    return __uint_as_float(((unsigned int)h) << 16);
}

// hi = RNE bf16 of x; lo = truncated bf16 of (x - hi). lo-term error lands at 2^-18 rel.
__device__ __forceinline__ void cvt_store(f32x4 a, f32x4 b,
                                          unsigned short* hd, unsigned short* ldst) {
    ushort8 hv, lv;
#pragma unroll
    for (int j = 0; j < 4; ++j) {
        unsigned short h = f2bf_rn(a[j]);
        hv[j] = h; lv[j] = (unsigned short)(__float_as_uint(a[j] - bf2f(h)) >> 16);
    }
#pragma unroll
    for (int j = 0; j < 4; ++j) {
        unsigned short h = f2bf_rn(b[j]);
        hv[j + 4] = h; lv[j + 4] = (unsigned short)(__float_as_uint(b[j] - bf2f(h)) >> 16);
    }
    *(ushort8*)hd = hv;
    *(ushort8*)ldst = lv;
}

// ---------------- pre: 3 roles in one launch (unchanged from round 8, verified) ----------
__global__ __launch_bounds__(256) void pre_kernel(const float* __restrict__ enc_w,
                                                  const float* __restrict__ enc_b,
                                                  const float* __restrict__ cb,
                                                  const float* __restrict__ dec_w,
                                                  const float* __restrict__ dec_b,
                                                  unsigned short* __restrict__ Wp,
                                                  float* __restrict__ c2,
                                                  float* __restrict__ Tdec,
                                                  int* __restrict__ counter) {
    const int t = threadIdx.x;
    const int lane = t & 63, wv = t >> 6;

    if (blockIdx.x < 48) {
        // ================= w2 GEMM role =================
        __shared__ float As[64][21];
        __shared__ float Bs[64][21];
        const int din0 = (blockIdx.x >> 2) * 64;
        const int col0 = (blockIdx.x & 3) * 64;
        const int tr = t >> 4, tc = t & 15;
        const int lr_ = t >> 2, k4 = (t & 3) * 4;

        float acc[4][4];
#pragma unroll
        for (int i = 0; i < 4; ++i)
#pragma unroll
            for (int j = 0; j < 4; ++j) acc[i][j] = 0.f;

        for (int k0 = 0; k0 < DD; k0 += 16) {
            {
                const float* ap = enc_w + (size_t)(din0 + lr_) * DD + k0 + k4;
                const float* bp = cb + (size_t)(col0 + lr_) * DD + k0 + k4;
                f32x4 av = *(const f32x4*)ap;
                f32x4 bv = *(const f32x4*)bp;
                *(f32x4*)&As[lr_][k4] = av;
                *(f32x4*)&Bs[lr_][k4] = bv;
            }
            __syncthreads();
#pragma unroll
            for (int kk = 0; kk < 16; ++kk) {
                float a[4], b[4];
#pragma unroll
                for (int i = 0; i < 4; ++i) a[i] = As[tr * 4 + i][kk];
#pragma unroll
                for (int j = 0; j < 4; ++j) b[j] = Bs[tc * 4 + j][kk];
#pragma unroll
                for (int i = 0; i < 4; ++i)
#pragma unroll
                    for (int j = 0; j < 4; ++j) acc[i][j] = fmaf(a[i], b[j], acc[i][j]);
            }
            __syncthreads();
        }
#pragma unroll
        for (int i = 0; i < 4; ++i) {
            int din = din0 + tr * 4 + i;
            size_t ub = (size_t)(din >> 5) * 2048 + (size_t)((din >> 3) & 3) * 256;
            int jj = din & 7;
#pragma unroll
            for (int j = 0; j < 4; ++j) {
                int col = col0 + tc * 4 + j;
                float w = -2.0f * acc[i][j];
                unsigned short h = f2bf_rn(w);
                unsigned short l = (unsigned short)(__float_as_uint(w - bf2f(h)) >> 16);
                size_t p = (ub + col) * 8 + jj;
                Wp[p] = h;
                Wp[p + 8192] = l;
            }
        }
    } else if (blockIdx.x == 48) {
        // ================= c2 role =================
        __shared__ float bb[DD];
        for (int d = t; d < DD; d += 256) bb[d] = enc_b[d];
        __syncthreads();
        for (int c4 = 0; c4 < 16; ++c4) {
            int col0 = wv * 64 + c4 * 4;
            const float* C0 = cb + (size_t)col0 * DD;
            const float* C1 = C0 + DD;
            const float* C2 = C0 + 2 * DD;
            const float* C3 = C0 + 3 * DD;
            float b0 = 0, b1 = 0, b2 = 0, b3 = 0, n0 = 0, n1 = 0, n2 = 0, n3 = 0;
#pragma unroll
            for (int i = 0; i < 8; ++i) {
                int d = lane + 64 * i;
                float b = bb[d];
                float c0v = C0[d], c1v = C1[d], c2v = C2[d], c3v = C3[d];
                b0 = fmaf(b, c0v, b0); n0 = fmaf(c0v, c0v, n0);
                b1 = fmaf(b, c1v, b1); n1 = fmaf(c1v, c1v, n1);
                b2 = fmaf(b, c2v, b2); n2 = fmaf(c2v, c2v, n2);
                b3 = fmaf(b, c3v, b3); n3 = fmaf(c3v, c3v, n3);
            }
#pragma unroll
            for (int off = 1; off < 64; off <<= 1) {
                b0 += __shfl_xor(b0, off); n0 += __shfl_xor(n0, off);
                b1 += __shfl_xor(b1, off); n1 += __shfl_xor(n1, off);
                b2 += __shfl_xor(b2, off); n2 += __shfl_xor(n2, off);
                b3 += __shfl_xor(b3, off); n3 += __shfl_xor(n3, off);
            }
            if (lane == 0) {
                c2[col0]     = -2.0f * b0 + n0;
                c2[col0 + 1] = -2.0f * b1 + n1;
                c2[col0 + 2] = -2.0f * b2 + n2;
                c2[col0 + 3] = -2.0f * b3 + n3;
            }
        }
        if (t == 0) *counter = 0;
    } else {
        // ================= chain role =================
        int k = blockIdx.x - 49;
        __shared__ float  q[DD];
        __shared__ float  Tsum[DD];
        __shared__ double wbest[4];
        __shared__ int    wbesti[4];
        __shared__ int    sel;

        for (int d = t; d < DD; d += 256) {
            float v = cb[(size_t)k * DD + d];
            q[d] = v; Tsum[d] = v;
        }

        for (int l = 1; l < 4; ++l) {
            __syncthreads();
            const float* C = cb + (size_t)l * KK * DD;
            double best = 1e300; int bi = 1 << 20;
            for (int c4 = 0; c4 < 16; ++c4) {
                int col0 = wv * 64 + c4 * 4;
                const float* C0 = C + (size_t)col0 * DD;
                const float* C1 = C0 + DD;
                const float* C2 = C0 + 2 * DD;
                const float* C3 = C0 + 3 * DD;
                float p0 = 0, p1 = 0, p2 = 0, p3 = 0, n0 = 0, n1 = 0, n2 = 0, n3 = 0;
#pragma unroll
                for (int i = 0; i < 8; ++i) {
                    int d = lane + 64 * i;
                    float qq = q[d];
                    float c0v = C0[d], c1v = C1[d], c2v = C2[d], c3v = C3[d];
                    p0 = fmaf(qq, c0v, p0); n0 = fmaf(c0v, c0v, n0);
                    p1 = fmaf(qq, c1v, p1); n1 = fmaf(c1v, c1v, n1);
                    p2 = fmaf(qq, c2v, p2); n2 = fmaf(c2v, c2v, n2);
                    p3 = fmaf(qq, c3v, p3); n3 = fmaf(c3v, c3v, n3);
                }
                double s0 = -2.0 * (double)p0 + (double)n0;
                double s1 = -2.0 * (double)p1 + (double)n1;
                double s2 = -2.0 * (double)p2 + (double)n2;
                double s3 = -2.0 * (double)p3 + (double)n3;
#pragma unroll
                for (int off = 1; off < 64; off <<= 1) {
                    s0 += __shfl_xor(s0, off);
                    s1 += __shfl_xor(s1, off);
                    s2 += __shfl_xor(s2, off);
                    s3 += __shfl_xor(s3, off);
                }
                if (s0 < best) { best = s0; bi = col0; }
                if (s1 < best) { best = s1; bi = col0 + 1; }
                if (s2 < best) { best = s2; bi = col0 + 2; }
                if (s3 < best) { best = s3; bi = col0 + 3; }
            }
            if (lane == 0) { wbest[wv] = best; wbesti[wv] = bi; }
            __syncthreads();
            if (t == 0) {
                double bv = wbest[0]; int bidx = wbesti[0];
                for (int g = 1; g < 4; ++g)
                    if (wbest[g] < bv || (wbest[g] == bv && wbesti[g] < bidx)) { bv = wbest[g]; bidx = wbesti[g]; }
                sel = bidx;
            }
            __syncthreads();
            const float* Cs = C + (size_t)sel * DD;
            for (int d = t; d < DD; d += 256) {
                float v = Cs[d];
                q[d] = v; Tsum[d] += v;
            }
        }
        __syncthreads();
        for (int n = t; n < DD; n += 256) {
            double a0 = 0, a1 = 0, a2 = 0, a3 = 0;
            for (int d = 0; d < DD; d += 4) {
                a0 += (double)Tsum[d]     * (double)dec_w[(size_t)(d)     * DD + n];
                a1 += (double)Tsum[d + 1] * (double)dec_w[(size_t)(d + 1) * DD + n];
                a2 += (double)Tsum[d + 2] * (double)dec_w[(size_t)(d + 2) * DD + n];
                a3 += (double)Tsum[d + 3] * (double)dec_w[(size_t)(d + 3) * DD + n];
            }
            Tdec[(size_t)k * DD + n] = (float)((double)dec_b[n] + a0 + a1 + a2 + a3);
        }
    }
}

// ---------------- bulk: reg-pipelined MFMA, NO in-loop vmcnt drain ----------------------
// grid 2048, block 256 (4 waves). Block tile 64x256; wave tile 64x64 (cg=wv).
// In-loop sync: lgkmcnt(0) + sched_barrier + raw s_barrier (register prefetches stay in
// flight across the barrier; compiler emits counted vmcnt at each consumer).
// wh double-buffered (1 step ahead); wl single-buffered, consumed by the LAST 16 MFMAs
// of the step (~600cy cover). nx = X(s+2) 2-step HBM prefetch (single buffer, cvt-then-reload).
__global__ __launch_bounds__(256, 2) void bulk_kernel(const float* __restrict__ X,
                                                      const unsigned short* __restrict__ Wp,
                                                      const float* __restrict__ c2,
                                                      const float* __restrict__ Tdec,
                                                      float* __restrict__ out,
                                                      int* __restrict__ counter,
                                                      int* __restrict__ list) {
    __shared__ __align__(16) unsigned short Xh[2][2048];   // 2 x 4KB (256 units x 16B)
    __shared__ __align__(16) unsigned short Xl[2][2048];   // 2 x 4KB
    __shared__ float Rv1[BM * 4];
    __shared__ float Rv2[BM * 4];
    __shared__ int   Ri1[BM * 4];
    __shared__ int   rowIdx[BM];

    const int t    = threadIdx.x;
    const int lane = t & 63;
    const int wv   = t >> 6;        // col-group 0..3 (64 cols each)
    const int lr   = lane & 15;
    const int lg   = lane >> 4;
    const int row0 = blockIdx.x * BM;

    f32x4 acc[4][4];
#pragma unroll
    for (int rf = 0; rf < 4; ++rf)
#pragma unroll
        for (int cf = 0; cf < 4; ++cf) acc[rf][cf] = (f32x4){0.f, 0.f, 0.f, 0.f};

    // X staging: thread t handles row=t>>2, k-subchunk=(t&3)*8
    const int xrow = t >> 2, xsub = t & 3;
    const float* xp_base = X + (size_t)(row0 + xrow) * DIN + xsub * 8;
    const int xu = (xsub * 64 + xrow) ^ (xsub << 1);   // XOR-swizzled unit (write side)

    // W frag lane-base: u = lg*256 + wv*64 + cf*16 + lr; hi at u*8, lo at (u+1024)*8
    const unsigned short* wlane = Wp + (size_t)(lg * 256 + wv * 64 + lr) * 8;

    f32x4 nxa, nxb;
    short8 wh[2][4], wl[4];

    // ---- prologue ----
    {
        f32x4 a = __builtin_nontemporal_load((const f32x4*)xp_base);
        f32x4 b = __builtin_nontemporal_load((const f32x4*)(xp_base + 4));
        cvt_store(a, b, &Xh[0][xu * 8], &Xl[0][xu * 8]);
        nxa = __builtin_nontemporal_load((const f32x4*)(xp_base + BK));
        nxb = __builtin_nontemporal_load((const f32x4*)(xp_base + BK + 4));
#pragma unroll
        for (int cf = 0; cf < 4; ++cf)
            wh[0][cf] = *(const short8*)(wlane + cf * 128);
    }
    __syncthreads();

#define HALF(P, S)                                                                          \
    {                                                                                       \
        const int s_ = (S);                                                                 \
        /* read X(s) fragments from LDS[P] */                                               \
        short8 ah[4], al[4];                                                                \
        _Pragma("unroll")                                                                   \
        for (int rf = 0; rf < 4; ++rf) {                                                    \
            int u = (lg * 64 + rf * 16 + lr) ^ (lg << 1);                                   \
            ah[rf] = *(const short8*)&Xh[P][u * 8];                                         \
            al[rf] = *(const short8*)&Xl[P][u * 8];                                         \
        }                                                                                   \
        /* issue WL(s) -- consumed by the last 16 MFMAs of THIS step */                     \
        {                                                                                   \
            const unsigned short* wsl = wlane + (size_t)s_ * 16384 + 8192;                  \
            _Pragma("unroll")                                                               \
            for (int cf = 0; cf < 4; ++cf)                                                  \
                wl[cf] = *(const short8*)(wsl + cf * 128);                                  \
        }                                                                                   \
        /* cvt X(s+1) -> LDS[P^1]; reload nx = X(s+2) */                                    \
        if (s_ + 1 < NSTEP)                                                                 \
            cvt_store(nxa, nxb, &Xh[(P) ^ 1][xu * 8], &Xl[(P) ^ 1][xu * 8]);                \
        if (s_ + 2 < NSTEP) {                                                               \
            nxa = __builtin_nontemporal_load((const f32x4*)(xp_base + (s_ + 2) * BK));      \
            nxb = __builtin_nontemporal_load((const f32x4*)(xp_base + (s_ + 2) * BK + 4));  \
        }                                                                                   \
        /* issue WH(s+1) -> wh[P^1] */                                                      \
        if (s_ + 1 < NSTEP) {                                                               \
            const unsigned short* wsh = wlane + (size_t)(s_ + 1) * 16384;                   \
            _Pragma("unroll")                                                               \
            for (int cf = 0; cf < 4; ++cf)                                                  \
                wh[(P) ^ 1][cf] = *(const short8*)(wsh + cf * 128);                         \
        }                                                                                   \
        /* ds reads done + ds writes visible; pin order; NO vmcnt drain */                  \
        asm volatile("s_waitcnt lgkmcnt(0)" ::: "memory");                                  \
        __builtin_amdgcn_sched_barrier(0);                                                  \
        __builtin_amdgcn_s_setprio(1);                                                      \
        _Pragma("unroll")                                                                   \
        for (int cf = 0; cf < 4; ++cf) {                                                    \
            _Pragma("unroll")                                                               \
            for (int rf = 0; rf < 4; ++rf) {                                                \
                acc[rf][cf] = __builtin_amdgcn_mfma_f32_16x16x32_bf16(al[rf], wh[P][cf], acc[rf][cf], 0, 0, 0); \
                acc[rf][cf] = __builtin_amdgcn_mfma_f32_16x16x32_bf16(ah[rf], wh[P][cf], acc[rf][cf], 0, 0, 0); \
            }                                                                               \
        }                                                                                   \
        _Pragma("unroll")                                                                   \
        for (int cf = 0; cf < 4; ++cf) {                                                    \
            _Pragma("unroll")                                                               \
            for (int rf = 0; rf < 4; ++rf) {                                                \
                acc[rf][cf] = __builtin_amdgcn_mfma_f32_16x16x32_bf16(ah[rf], wl[cf], acc[rf][cf], 0, 0, 0); \
            }                                                                               \
        }                                                                                   \
        __builtin_amdgcn_s_setprio(0);                                                      \
        __builtin_amdgcn_s_barrier();                                                       \
    }

#pragma unroll 1
    for (int s2 = 0; s2 < NSTEP / 2; ++s2) {
        HALF(0, 2 * s2);
        HALF(1, 2 * s2 + 1);
    }
#undef HALF

    __syncthreads();   // full drain once before LDS reuse / epilogue

    // --- epilogue: per-row top-2 (C/D layout: col=lane&15, row=(lane>>4)*4+reg) ---
    float c2v[4];
#pragma unroll
    for (int cf = 0; cf < 4; ++cf) c2v[cf] = c2[wv * 64 + cf * 16 + lr];

#pragma unroll
    for (int rf = 0; rf < 4; ++rf) {
#pragma unroll
        for (int reg = 0; reg < 4; ++reg) {
            float v1 = 3.4e38f, v2 = 3.4e38f;
            int   c1 = 1 << 20;
#pragma unroll
            for (int cf = 0; cf < 4; ++cf) {
                float sc = acc[rf][cf][reg] + c2v[cf];
                int col = wv * 64 + cf * 16 + lr;
                if (sc < v1 || (sc == v1 && col < c1)) { v2 = v1; v1 = sc; c1 = col; }
                else if (sc < v2) v2 = sc;
            }
#pragma unroll
            for (int off = 1; off < 16; off <<= 1) {
                float ov1 = __shfl_xor(v1, off);
                float ov2 = __shfl_xor(v2, off);
                int   oc1 = __shfl_xor(c1, off);
                if (ov1 < v1 || (ov1 == v1 && oc1 < c1)) { v2 = fminf(v1, ov2); v1 = ov1; c1 = oc1; }
                else v2 = fminf(v2, ov1);
            }
            if (lr == 0) {
                int r = rf * 16 + lg * 4 + reg;
                Rv1[r * 4 + wv] = v1; Ri1[r * 4 + wv] = c1; Rv2[r * 4 + wv] = v2;
            }
        }
    }
    __syncthreads();

    if (t < BM) {
        float v1 = Rv1[t * 4], v2 = Rv2[t * 4];
        int   c1 = Ri1[t * 4];
#pragma unroll
        for (int g = 1; g < 4; ++g) {
            float bv = Rv1[t * 4 + g], bs = Rv2[t * 4 + g];
            int   bc = Ri1[t * 4 + g];
            if (bv < v1) { v2 = fminf(v1, bs); v1 = bv; c1 = bc; }
            else         { v2 = fminf(v2, bv); }
        }
        rowIdx[t] = c1;
        if (v2 - v1 < MARGIN_TH) {
            int pos = atomicAdd(counter, 1);
            list[pos] = row0 + t;
        }
    }
    __syncthreads();

    // --- gather + write: 64 rows x 512 f32, coalesced f32x4, nontemporal ---
#pragma unroll
    for (int m = 0; m < 32; ++m) {
        int lin = m * 256 + t;            // 0..8191
        int r   = lin >> 7;               // 0..63
        int c4  = (lin & 127) * 4;
        f32x4 v = *(const f32x4*)(Tdec + (size_t)rowIdx[r] * DD + c4);
        __builtin_nontemporal_store(v, (f32x4*)(out + (size_t)(row0 + r) * DD + c4));
    }
}

// ---------------- refine: fp64-exact re-decision for near-tie rows ----------------------
__global__ __launch_bounds__(256) void refine_kernel(const float* __restrict__ X,
                                                     const float* __restrict__ enc_w,
                                                     const float* __restrict__ enc_b,
                                                     const float* __restrict__ cb,
                                                     const float* __restrict__ Tdec,
                                                     float* __restrict__ out,
                                                     const int* __restrict__ counter,
                                                     const int* __restrict__ list) {
    int cnt = *counter;
    __shared__ double r0[DD];
    __shared__ double sv[256];
    __shared__ int    si[256];
    for (int it = blockIdx.x; it < cnt; it += gridDim.x) {
        int n = list[it];
        const float* xr = X + (size_t)n * DIN;
        for (int d = threadIdx.x; d < DD; d += 256) {
            double a0 = 0, a1 = 0, a2 = 0, a3 = 0;
            for (int j = 0; j < DIN; j += 4) {
                a0 += (double)xr[j]     * (double)enc_w[(size_t)(j)     * DD + d];
                a1 += (double)xr[j + 1] * (double)enc_w[(size_t)(j + 1) * DD + d];
                a2 += (double)xr[j + 2] * (double)enc_w[(size_t)(j + 2) * DD + d];
                a3 += (double)xr[j + 3] * (double)enc_w[(size_t)(j + 3) * DD + d];
            }
            r0[d] = (double)enc_b[d] + a0 + a1 + a2 + a3;
        }
        __syncthreads();
        int k = threadIdx.x;
        const float* ck = cb + (size_t)k * DD;
        double d0 = 0, d1 = 0, n0 = 0, n1 = 0;
        for (int d = 0; d < DD; d += 2) {
            double c0 = ck[d], c1 = ck[d + 1];
            d0 += r0[d] * c0;     n0 += c0 * c0;
            d1 += r0[d + 1] * c1; n1 += c1 * c1;
        }
        sv[k] = -2.0 * (d0 + d1) + (n0 + n1); si[k] = k;
        __syncthreads();
        for (int off = 128; off; off >>= 1) {
            if (k < off) {
                double a = sv[k], b = sv[k + off];
                if (b < a || (b == a && si[k + off] < si[k])) { sv[k] = b; si[k] = si[k + off]; }
            }
            __syncthreads();
        }
        int best = si[0];
        for (int c = threadIdx.x; c < DD; c += 256)
            out[(size_t)n * DD + c] = Tdec[(size_t)best * DD + c];
        __syncthreads();
    }
}

extern "C" void kernel_launch(void* const* d_in, const int* in_sizes, int n_in,
                              void* d_out, int out_size, void* d_ws, size_t ws_size,
                              hipStream_t stream) {
    const float* X     = (const float*)d_in[0];
    const float* enc_w = (const float*)d_in[1];
    const float* enc_b = (const float*)d_in[2];
    const float* cb    = (const float*)d_in[3];
    const float* dec_w = (const float*)d_in[4];
    const float* dec_b = (const float*)d_in[5];
    float* out = (float*)d_out;

    char* ws = (char*)d_ws;
    unsigned short* Wp = (unsigned short*)(ws + 0);          // 24*2048*8*2B = 786432
    float* c2      = (float*)(ws + 786432);                  // 1024
    float* Tdec    = (float*)(ws + 787456);                  // 524288
    int*   counter = (int*)  (ws + 1311744);                 // 4 (+pad)
    int*   list    = (int*)  (ws + 1311776);                 // near-tie rows

    hipLaunchKernelGGL(pre_kernel,   dim3(305),        dim3(256), 0, stream,
                       enc_w, enc_b, cb, dec_w, dec_b, Wp, c2, Tdec, counter);
    hipLaunchKernelGGL(bulk_kernel,  dim3(NROWS / BM), dim3(256), 0, stream,
                       X, Wp, c2, Tdec, out, counter, list);
    hipLaunchKernelGGL(refine_kernel, dim3(1024),      dim3(256), 0, stream,
                       X, enc_w, enc_b, cb, Tdec, out, counter, list);
}